// Round 5
// baseline (414.355 us; speedup 1.0000x reference)
//
#include <hip/hip_runtime.h>
#include <hip/hip_bf16.h>
#include <math.h>

#define EPS 1e-5f

static constexpr int N_ = 128, C_ = 128, T_ = 256, V_ = 21, E_ = 8, M_ = 13;
static constexpr int TV_ = T_ * V_;   // 5376
static constexpr int NT_ = 4;         // t's per main block
static constexpr int ST_ = NT_ * V_;  // 84 s-columns per block
static constexpr int SROWS = 96;      // padded to 6 MFMA N-frags
static constexpr int XF_PITCH = 48;   // bytes per xf row (24 bf16 slots, 21 used)
static constexpr int LDS_BYTES = SROWS * 256 + 64;  // 24640 (staging & xf overlap + tail pad)

// staging-buffer swizzle: varies with both (s&7) and (s>>3) so strided writers spread
#define SWZ(s)  (((((s) & 7) ^ ((((s) >> 3) & 3) << 1))) << 4)
// xf-buffer row xor: bijective within each 32-row group (reader uses identical xor)
#define EXOR(r) ((((r) >> 5) & 3) << 4)

typedef short bf16x8 __attribute__((ext_vector_type(8)));
typedef short s16x4  __attribute__((ext_vector_type(4)));
typedef float f32x4  __attribute__((ext_vector_type(4)));

__device__ inline short f2bf(float v) {
    __hip_bfloat16 b = __float2bfloat16(v);
    return *reinterpret_cast<short*>(&b);
}

// ---------------- Kernel P: fold BN + convert W to bf16 ----------------
__global__ __launch_bounds__(256) void prep_kernel(
    const float* __restrict__ ft_w, const float* __restrict__ ft_b,
    const float* __restrict__ ft_gamma, const float* __restrict__ ft_beta,
    const float* __restrict__ ft_mean, const float* __restrict__ ft_var,
    __hip_bfloat16* __restrict__ w_bf, float* __restrict__ sc_g, float* __restrict__ sh_g)
{
    int tid = blockIdx.x * 256 + threadIdx.x;
    if (tid < C_ * C_) w_bf[tid] = __float2bfloat16(ft_w[tid]);
    if (tid < C_) {
        float sc = ft_gamma[tid] * rsqrtf(ft_var[tid] + EPS);
        sc_g[tid] = sc;
        sh_g[tid] = (ft_b[tid] - ft_mean[tid]) * sc + ft_beta[tid];
    }
}

// ---------------- Kernel A: mean over T ----------------
__global__ __launch_bounds__(256) void mean_kernel(const float* __restrict__ x,
                                                   float* __restrict__ xm) {
    __shared__ float slab[TV_];
    __shared__ float partial[V_ * 8];
    const int nc = blockIdx.x;
    const int tid = threadIdx.x;
    const float4* src4 = (const float4*)(x + (size_t)nc * TV_);
    float4* slab4 = (float4*)slab;
    #pragma unroll
    for (int it = 0; it < 6; ++it) {
        int idx = it * 256 + tid;
        if (idx < TV_ / 4) slab4[idx] = src4[idx];
    }
    __syncthreads();
    if (tid < V_ * 8) {
        int v = tid >> 3, g = tid & 7;
        float s = 0.f;
        #pragma unroll
        for (int tt = 0; tt < 32; ++tt) s += slab[(g * 32 + tt) * V_ + v];
        partial[v * 8 + g] = s;
    }
    __syncthreads();
    if (tid < V_) {
        float s = 0.f;
        #pragma unroll
        for (int g = 0; g < 8; ++g) s += partial[tid * 8 + g];
        xm[(size_t)nc * V_ + tid] = s * (1.0f / T_);
    }
}

// ---------------- Kernel B: H_dyn + A = H^T H (bf16, 32x32 zero-padded) ----------------
__global__ __launch_bounds__(64) void hyper_kernel(
    const float* __restrict__ xm, const float* __restrict__ dyn_w,
    const float* __restrict__ dyn_b,
    const float* __restrict__ dyn_gamma, const float* __restrict__ dyn_beta,
    const float* __restrict__ dyn_mean, const float* __restrict__ dyn_var,
    __hip_bfloat16* __restrict__ A_bf)               // (N,32,32)
{
    __shared__ float xs[C_ * V_];
    __shared__ float Hs[M_ * V_];
    const int n = blockIdx.x;
    const int l = threadIdx.x;
    const float* src = xm + (size_t)n * C_ * V_;
    for (int idx = l; idx < C_ * V_; idx += 64) xs[idx] = src[idx];
    __syncthreads();
    for (int idx = l; idx < E_ * V_; idx += 64) {
        int e = idx / V_, v = idx - e * V_;
        float acc = 0.f;
        for (int c = 0; c < C_; ++c) acc = fmaf(xs[c * V_ + v], dyn_w[e * C_ + c], acc);
        acc += dyn_b[e];
        float scale = dyn_gamma[e] * rsqrtf(dyn_var[e] + EPS);
        acc = (acc - dyn_mean[e]) * scale + dyn_beta[e];
        Hs[idx] = fmaxf(acc, 0.f);
    }
    __syncthreads();
    if (l < E_) {
        float row[V_];
        float mx = -1e30f;
        #pragma unroll
        for (int v = 0; v < V_; ++v) { row[v] = Hs[l * V_ + v]; mx = fmaxf(mx, row[v]); }
        float s = 0.f;
        #pragma unroll
        for (int v = 0; v < V_; ++v) { row[v] = __expf(row[v] - mx); s += row[v]; }
        float inv = 1.0f / s;
        #pragma unroll
        for (int v = 0; v < V_; ++v) Hs[l * V_ + v] = row[v] * inv;
    } else if (l < M_) {
        int i = l - E_;
        #pragma unroll
        for (int v = 0; v < V_; ++v)
            Hs[l * V_ + v] = (v >= 1 + 4 * i && v < 5 + 4 * i) ? 1.0f : 0.0f;
    }
    __syncthreads();
    for (int idx = l; idx < 32 * 32; idx += 64) {
        int u = idx >> 5, v = idx & 31;
        float s = 0.f;
        if (u < V_ && v < V_) {
            #pragma unroll
            for (int m = 0; m < M_; ++m) s = fmaf(Hs[m * V_ + u], Hs[m * V_ + v], s);
        }
        A_bf[(size_t)n * 1024 + idx] = __float2bfloat16(s);
    }
}

// ---------------- Kernel C: MFMA GEMM + BN/ReLU + MFMA A-transform + residual ----------------
// grid (64 s-tiles, 128 n), 512 threads = 8 waves. Wave w owns o in [16w, 16w+16).
__global__ __launch_bounds__(512, 8) void main_kernel(
    const float* __restrict__ x, const __hip_bfloat16* __restrict__ w_bf,
    const float* __restrict__ sc_g, const float* __restrict__ sh_g,
    const __hip_bfloat16* __restrict__ A_bf, float* __restrict__ out)
{
    // phase 1: X_t[s=96][c=128] bf16 swizzled (24576 B)
    // phase 2: xf[(o*4+t)=512][24 bf16] pitch 48 B (24576 B) + 64 B zeroed tail
    __shared__ __align__(16) char lds[LDS_BYTES];
    __shared__ float sc_s[C_], sh_s[C_];

    const int st = blockIdx.x;    // 0..63
    const int n  = blockIdx.y;    // 0..127
    const int tid = threadIdx.x;
    const int w = tid >> 6;       // wave 0..7
    const int l = tid & 63;       // lane
    const int hi = l >> 4;        // 0..3
    const int lo = l & 15;
    const int s0 = st * ST_;
    const size_t xbase = (size_t)n * C_ * TV_ + s0;

    if (tid < C_) { sc_s[tid] = sc_g[tid]; sh_s[tid] = sh_g[tid]; }

    // W fragments (GEMM1 A-operand): lane holds W[16w+lo][kk*32 + 8*hi + j]
    const int o_row = 16 * w + lo;
    bf16x8 wf[4];
    #pragma unroll
    for (int kk = 0; kk < 4; ++kk)
        wf[kk] = *(const bf16x8*)((const short*)w_bf + o_row * C_ + kk * 32 + 8 * hi);

    // GEMM2 B-fragments from global A_bf (L2-hot; A symmetric so row-frags == col-frags)
    const short* Abf_n = (const short*)A_bf + (size_t)n * 1024;
    const bf16x8 bA0 = *(const bf16x8*)(Abf_n + lo * 32 + 8 * hi);         // v = 0..15
    const bf16x8 bA1 = *(const bf16x8*)(Abf_n + (16 + lo) * 32 + 8 * hi);  // v = 16..31

    // ---- stage X_t[s][c] bf16 (672 work items: 4 c's x 4 s's each) ----
    auto stage_one = [&](int idx) {
        int cg = idx / 21, q = idx - cg * 21;
        int c0 = cg * 4, sq = q * 4;
        f32x4 f[4];
        #pragma unroll
        for (int i = 0; i < 4; ++i)
            f[i] = *(const f32x4*)(x + xbase + (size_t)(c0 + i) * TV_ + sq);
        #pragma unroll
        for (int i = 0; i < 4; ++i) {
            int s = sq + i;
            s16x4 pk;
            #pragma unroll
            for (int j = 0; j < 4; ++j) pk[j] = f2bf(f[j][i]);
            int byte = (s * 256 + c0 * 2) ^ SWZ(s);
            *(s16x4*)(lds + byte) = pk;
        }
    };
    stage_one(tid);
    if (tid < 672 - 512) stage_one(tid + 512);

    // zero pad rows s = 84..95
    if (tid < 384) {
        int srow = ST_ + (tid >> 5);
        int k = tid & 31;
        int byte = (srow * 256 + k * 8) ^ SWZ(srow);
        *(unsigned long long*)(lds + byte) = 0ull;
    }
    __syncthreads();

    // ---- GEMM1: 6 N-frags, K = 128 in 4 steps ----
    f32x4 acc[6];
    #pragma unroll
    for (int nf = 0; nf < 6; ++nf) acc[nf] = (f32x4){0.f, 0.f, 0.f, 0.f};
    #pragma unroll
    for (int kk = 0; kk < 4; ++kk) {
        #pragma unroll
        for (int nf = 0; nf < 6; ++nf) {
            int srow = 16 * nf + lo;
            int byte = (srow * 256 + (kk * 32 + 8 * hi) * 2) ^ SWZ(srow);
            bf16x8 b = *(const bf16x8*)(lds + byte);
            acc[nf] = __builtin_amdgcn_mfma_f32_16x16x32_bf16(wf[kk], b, acc[nf], 0, 0, 0);
        }
    }
    __syncthreads();   // staging reads complete; buffer becomes xf

    // ---- BN + ReLU -> xf bf16 at row (o*4+t), col u; pitch 48 B, row-xor EXOR ----
    const int obase = 16 * w + 4 * hi;
    float scr[4], shr[4];
    #pragma unroll
    for (int r = 0; r < 4; ++r) { scr[r] = sc_s[obase + r]; shr[r] = sh_s[obase + r]; }
    #pragma unroll
    for (int nf = 0; nf < 6; ++nf) {
        int s = 16 * nf + lo;
        if (s < ST_) {
            int t = s / V_, u = s - t * V_;
            #pragma unroll
            for (int r = 0; r < 4; ++r) {
                float vv = fmaxf(fmaf(acc[nf][r], scr[r], shr[r]), 0.f);
                int row = (obase + r) * NT_ + t;
                *(short*)(lds + ((row * XF_PITCH + u * 2) ^ EXOR(row))) = f2bf(vv);
            }
        }
    }
    // zero the u=21..23 pad of every row + the 64 B tail (NaN-safety for k>=21 reads)
    {
        int row = tid;             // 512 threads == 512 rows
        int e = EXOR(row);
        *(short*)(lds + ((row * XF_PITCH + 42) ^ e)) = 0;
        *(int*)(lds + ((row * XF_PITCH + 44) ^ e)) = 0;
    }
    if (tid < 16) *(int*)(lds + SROWS * 256 + tid * 4) = 0;
    __syncthreads();

    // ---- GEMM2: Xr = xf (512x32) * A (32x32); wave w owns M-frags 4w..4w+3 ----
    bf16x8 xfr[4];
    #pragma unroll
    for (int i = 0; i < 4; ++i) {
        int row = 16 * (4 * w + i) + lo;
        xfr[i] = *(const bf16x8*)(lds + ((row * XF_PITCH + 16 * hi) ^ EXOR(row)));
    }
    #pragma unroll
    for (int i = 0; i < 4; ++i) {
        f32x4 d0 = (f32x4){0.f, 0.f, 0.f, 0.f};
        f32x4 d1 = (f32x4){0.f, 0.f, 0.f, 0.f};
        d0 = __builtin_amdgcn_mfma_f32_16x16x32_bf16(xfr[i], bA0, d0, 0, 0, 0);
        d1 = __builtin_amdgcn_mfma_f32_16x16x32_bf16(xfr[i], bA1, d1, 0, 0, 0);
        int row0 = 16 * (4 * w + i) + 4 * hi;
        #pragma unroll
        for (int r = 0; r < 4; ++r) {
            int row = row0 + r;
            int o = row >> 2, t = row & 3;
            size_t g = xbase + (size_t)o * TV_ + t * V_;
            out[g + lo] = d0[r] + x[g + lo];
            if (lo < V_ - 16) out[g + 16 + lo] = d1[r] + x[g + 16 + lo];
        }
    }
}

extern "C" void kernel_launch(void* const* d_in, const int* in_sizes, int n_in,
                              void* d_out, int out_size, void* d_ws, size_t ws_size,
                              hipStream_t stream) {
    const float* x         = (const float*)d_in[0];
    const float* dyn_w     = (const float*)d_in[1];
    const float* dyn_b     = (const float*)d_in[2];
    const float* dyn_gamma = (const float*)d_in[3];
    const float* dyn_beta  = (const float*)d_in[4];
    const float* dyn_mean  = (const float*)d_in[5];
    const float* dyn_var   = (const float*)d_in[6];
    const float* ft_w      = (const float*)d_in[7];
    const float* ft_b      = (const float*)d_in[8];
    const float* ft_gamma  = (const float*)d_in[9];
    const float* ft_beta   = (const float*)d_in[10];
    const float* ft_mean   = (const float*)d_in[11];
    const float* ft_var    = (const float*)d_in[12];
    float* out = (float*)d_out;

    char* ws = (char*)d_ws;
    float* xm  = (float*)ws;                                   ws += (size_t)N_ * C_ * V_ * 4;
    __hip_bfloat16* A_bf = (__hip_bfloat16*)ws;                ws += (size_t)N_ * 1024 * 2;
    __hip_bfloat16* w_bf = (__hip_bfloat16*)ws;                ws += (size_t)C_ * C_ * 2;
    float* sc_g = (float*)ws;                                  ws += C_ * 4;
    float* sh_g = (float*)ws;                                  ws += C_ * 4;

    prep_kernel<<<64, 256, 0, stream>>>(ft_w, ft_b, ft_gamma, ft_beta, ft_mean, ft_var,
                                        w_bf, sc_g, sh_g);
    mean_kernel<<<N_ * C_, 256, 0, stream>>>(x, xm);
    hyper_kernel<<<N_, 64, 0, stream>>>(xm, dyn_w, dyn_b, dyn_gamma, dyn_beta,
                                        dyn_mean, dyn_var, A_bf);
    main_kernel<<<dim3(T_ / NT_, N_), 512, 0, stream>>>(x, w_bf, sc_g, sh_g, A_bf, out);
}